// Round 13
// baseline (301.350 us; speedup 1.0000x reference)
//
#include <hip/hip_runtime.h>

#define D 128
#define SB 256
#define SI 8
#define SCHUNK (SB * SI)

typedef __attribute__((ext_vector_type(8))) short bf16x8;
typedef __attribute__((ext_vector_type(4))) float f32x4;
typedef unsigned int uint32;
typedef unsigned short ushort;

__device__ __forceinline__ ushort bf16rne(float f) {
  uint32 u = __float_as_uint(f);
  uint32 r = u + 0x7FFFu + ((u >> 16) & 1u);
  return (ushort)(r >> 16);
}
__device__ __forceinline__ float bf2f_lo(uint32 h) { return __uint_as_float(h << 16); }
__device__ __forceinline__ float bf2f_hi(uint32 h) { return __uint_as_float(h & 0xFFFF0000u); }
__device__ __forceinline__ uint32 packbf2(float x, float y) {
  return (uint32)bf16rne(x) | ((uint32)bf16rne(y) << 16);
}
__device__ __forceinline__ void acc8(float* a, float w, uint4 h) {
  a[0] += w * bf2f_lo(h.x); a[1] += w * bf2f_hi(h.x);
  a[2] += w * bf2f_lo(h.y); a[3] += w * bf2f_hi(h.y);
  a[4] += w * bf2f_lo(h.z); a[5] += w * bf2f_hi(h.z);
  a[6] += w * bf2f_lo(h.w); a[7] += w * bf2f_hi(h.w);
}

// ---------------- prep: xb convert + degree count + W-conv, one launch -----

__global__ void prep_kernel(const float* __restrict__ x, ushort* __restrict__ xb, int total4,
                            const int* __restrict__ dst, int* __restrict__ cnt, int E,
                            const float* __restrict__ W1, const float* __restrict__ W2,
                            const float* __restrict__ W3, ushort* __restrict__ Wf,
                            int xbB, int cntB) {
  int b = blockIdx.x;
  int tid = threadIdx.x;
  if (b < xbB) {
    int i = b * 256 + tid;
    if (i < total4) {
      float4 v = ((const float4*)x)[i];
      uint2 o;
      o.x = packbf2(v.x, v.y);
      o.y = packbf2(v.z, v.w);
      ((uint2*)xb)[i] = o;
    }
  } else if (b < xbB + cntB) {
    int e = (b - xbB) * 256 + tid;
    if (e < E) atomicAdd(&cnt[dst[e]], 1);
  } else {
    int idx = (b - xbB - cntB) * 256 + tid;  // 0..98303
    int which = idx >> 15;
    int id = idx & 32767;
    const float* W = (which == 0) ? W1 : ((which == 1) ? W2 : W3);
    int j = id & 7;
    int l = (id >> 3) & 63;
    int f = id >> 9;
    int p = f & 1, kc = (f >> 1) & 3, ct = f >> 3;
    int k = kc * 32 + (l >> 4) * 8 + j;
    int col = ct * 16 + (l & 15);
    float w = W[k * D + col];
    ushort hi = bf16rne(w);
    ushort outv = hi;
    if (p) {
      float hf = __uint_as_float((uint32)hi << 16);
      outv = bf16rne(w - hf);
    }
    Wf[idx] = outv;
  }
}

// ---------------- CSR build ----------------

__global__ void scan1_kernel(const int* __restrict__ cnt, int* __restrict__ off,
                             int* __restrict__ bsum, float* __restrict__ dis, int n) {
  __shared__ int tsum[SB];
  int tid = threadIdx.x;
  int base = blockIdx.x * SCHUNK;
  int v[SI];
  int s = 0;
#pragma unroll
  for (int i = 0; i < SI; i++) {
    int idx = base + tid * SI + i;
    v[i] = (idx < n) ? cnt[idx] : 0;
    s += v[i];
  }
  tsum[tid] = s;
  __syncthreads();
  for (int o = 1; o < SB; o <<= 1) {
    int t = (tid >= o) ? tsum[tid - o] : 0;
    __syncthreads();
    tsum[tid] += t;
    __syncthreads();
  }
  int run = tsum[tid] - s;
#pragma unroll
  for (int i = 0; i < SI; i++) {
    int idx = base + tid * SI + i;
    if (idx < n) {
      off[idx] = run;
      dis[idx] = rsqrtf((float)(v[i] + 1));
    }
    run += v[i];
  }
  if (tid == SB - 1) bsum[blockIdx.x] = tsum[tid];
}

// scan3: adds cross-chunk base (computed in-kernel from bsum; nb <= 64)
__global__ void scan3_kernel(int* __restrict__ off, const int* __restrict__ bsum,
                             int n, int total) {
  __shared__ int cbase;
  int b = blockIdx.x;
  int tid = threadIdx.x;
  int c = (b * 256) / SCHUNK;  // whole block lies in one chunk
  if (tid < 64) {
    int v = (tid < c) ? bsum[tid] : 0;
#pragma unroll
    for (int o = 32; o; o >>= 1) v += __shfl_down(v, o);
    if (tid == 0) cbase = v;
  }
  __syncthreads();
  int i = b * 256 + tid;
  if (i < n) off[i] += cbase;
  if (i == 0) off[n] = total;
}

// fill: uses cnt as countdown cursor (destroys it -> cnt ends all-zero)
__global__ void fill_kernel(const int* __restrict__ src, const int* __restrict__ dst,
                            const int* __restrict__ off, int* __restrict__ cnt,
                            uint2* __restrict__ epack, const float* __restrict__ dis, int E) {
  int e = blockIdx.x * blockDim.x + threadIdx.x;
  if (e >= E) return;
  int s = src[e], d = dst[e];
  int slot = atomicSub(&cnt[d], 1) - 1;
  int p = off[d] + slot;
  uint2 v;
  v.x = (uint32)s;
  v.y = __float_as_uint(dis[s] * dis[d]);
  epack[p] = v;
}

// ------- fused layer: out = [relu](Agg(t) @ W + bias) ----------------------
// gather-first. M=32 rows/block, 128 threads (2 waves), 8KB LDS.
// Register diet for 8 waves/SIMD: acc split into two 4-column halves
// (16 AGPRs), bf_ loaded per-kc, bias per-ct. Budget: (128,8) = 64 regs.

template <int FINAL>
__global__ __launch_bounds__(128, 8) void fused_kernel(const ushort* __restrict__ t,
                                                       const uint2* __restrict__ epack,
                                                       const int* __restrict__ off,
                                                       const float* __restrict__ dis,
                                                       const ushort* __restrict__ Wf,
                                                       const float* __restrict__ bias,
                                                       void* __restrict__ outp, int N) {
  __shared__ char lds[8192];
  int tid = threadIdx.x;
  int row0 = blockIdx.x * 32;
  int lane = tid & 63, wv = tid >> 6;  // wv 0..1
  int q = lane & 15, g = lane >> 4;
  int qb = q * 16;
  const char* tb = (const char*)t;

#pragma unroll 1
  for (int n4 = 0; n4 < 4; n4++) {
    int r = wv * 16 + n4 * 4 + g;  // 0..31
    int node = row0 + r;
    float a[8];
#pragma unroll
    for (int i = 0; i < 8; i++) a[i] = 0.f;

    if (node < N) {
      uint4 hs = *(const uint4*)(tb + (((uint32)node << 8) + qb));
      int j0 = off[node], j1 = off[node + 1];
      float dsv = dis[node];
      float sw = dsv * dsv;

      auto ldE = [&](int idx) -> uint2 {
        if (idx < j1) return epack[idx];
        uint2 z; z.x = (uint32)node; z.y = 0u; return z;  // self row, weight 0
      };
      int j = j0;
      uint2 e0 = ldE(j), e1 = ldE(j + 1), e2 = ldE(j + 2), e3 = ldE(j + 3);
      while (j < j1) {
        uint4 h0 = *(const uint4*)(tb + ((e0.x << 8) + qb));
        uint4 h1 = *(const uint4*)(tb + ((e1.x << 8) + qb));
        uint4 h2 = *(const uint4*)(tb + ((e2.x << 8) + qb));
        uint4 h3 = *(const uint4*)(tb + ((e3.x << 8) + qb));
        float w0 = __uint_as_float(e0.y), w1 = __uint_as_float(e1.y);
        float w2 = __uint_as_float(e2.y), w3 = __uint_as_float(e3.y);
        int jn = j + 4;
        e0 = ldE(jn); e1 = ldE(jn + 1); e2 = ldE(jn + 2); e3 = ldE(jn + 3);
        acc8(a, w0, h0);
        acc8(a, w1, h1);
        acc8(a, w2, h2);
        acc8(a, w3, h3);
        j = jn;
      }
      acc8(a, sw, hs);
    }
    uint4 pv;
    pv.x = packbf2(a[0], a[1]);
    pv.y = packbf2(a[2], a[3]);
    pv.z = packbf2(a[4], a[5]);
    pv.w = packbf2(a[6], a[7]);
    int boff = (r * 256 + qb) ^ ((r & 7) << 4);
    *(uint4*)(lds + boff) = pv;
  }
  __syncthreads();

  // ---- MFMA: z(32x128) @ W(128x128), split into two 4-column halves ----
  int lr = lane & 15, lg = lane >> 4;
  int m0 = wv * 16;

  bf16x8 af[4];
#pragma unroll
  for (int kc = 0; kc < 4; kc++) {
    int row = m0 + lr;
    int boff = (row * 256 + kc * 64 + lg * 16) ^ ((row & 7) << 4);
    af[kc] = *(bf16x8*)(lds + boff);
  }
  __syncthreads();  // all waves hold af; LDS now reusable for epilogue

#pragma unroll 1
  for (int hp = 0; hp < 2; hp++) {
    f32x4 acc4[4];
#pragma unroll
    for (int c4 = 0; c4 < 4; c4++) acc4[c4] = (f32x4){0.f, 0.f, 0.f, 0.f};

#pragma unroll 1
    for (int c4 = 0; c4 < 4; c4++) {
      int ct = hp * 4 + c4;
#pragma unroll 1
      for (int kc = 0; kc < 4; kc++) {
        bf16x8 b0 = *(const bf16x8*)&Wf[(size_t)((((ct * 4 + kc) * 2 + 0) * 64 + lane) * 8)];
        bf16x8 b1 = *(const bf16x8*)&Wf[(size_t)((((ct * 4 + kc) * 2 + 1) * 64 + lane) * 8)];
        acc4[c4] = __builtin_amdgcn_mfma_f32_16x16x32_bf16(af[kc], b0, acc4[c4], 0, 0, 0);
        acc4[c4] = __builtin_amdgcn_mfma_f32_16x16x32_bf16(af[kc], b1, acc4[c4], 0, 0, 0);
      }
    }

    if (FINAL) {
      // fp32 epilogue for this 64-column half
      float* out = (float*)outp;
#pragma unroll
      for (int c4 = 0; c4 < 4; c4++) {
        float bv = bias[(hp * 4 + c4) * 16 + lr];
#pragma unroll
        for (int r = 0; r < 4; r++) {
          int row = m0 + lg * 4 + r;
          int colb = c4 * 16 + lr;  // 0..63 within half
          float v = acc4[c4][r] + bv;
          int boff = (row * 256 + colb * 4) ^ ((row & 7) << 4);
          *(float*)(lds + boff) = v;
        }
      }
      __syncthreads();
#pragma unroll
      for (int i = 0; i < 4; i++) {
        int f = i * 2048 + tid * 16;  // 8KB: all 32 rows x 64 cols fp32
        int row = f >> 8;             // 0..31
        int boff = f ^ ((row & 7) << 4);
        if (row0 + row < N) {
          uint4 v = *(uint4*)(lds + boff);
          *(uint4*)((char*)out + (size_t)(row0 + row) * 512 + hp * 256 + (f & 255)) = v;
        }
      }
      __syncthreads();
    } else {
      // bf16 epilogue (bias+relu) for this 64-column half
#pragma unroll
      for (int c4 = 0; c4 < 4; c4++) {
        int col = (hp * 4 + c4) * 16 + lr;
        float bv = bias[col];
#pragma unroll
        for (int r = 0; r < 4; r++) {
          int row = m0 + lg * 4 + r;
          float v = fmaxf(acc4[c4][r] + bv, 0.f);
          int boff = (row * 256 + col * 2) ^ ((row & 7) << 4);
          *(ushort*)(lds + boff) = bf16rne(v);
        }
      }
      __syncthreads();
      ushort* outb = (ushort*)outp;
#pragma unroll
      for (int i = 0; i < 2; i++) {
        int f2 = i * 2048 + tid * 16;  // 4KB: 32 rows x 128B half-rows
        int row = f2 >> 7;             // 0..31
        int cb = f2 & 127;
        int boff = (row * 256 + hp * 128 + cb) ^ ((row & 7) << 4);
        if (row0 + row < N) {
          uint4 v = *(uint4*)(lds + boff);
          *(uint4*)((char*)outb + (size_t)(row0 + row) * 256 + hp * 128 + cb) = v;
        }
      }
      __syncthreads();
    }
  }
}

// ---------------- launch ----------------

extern "C" void kernel_launch(void* const* d_in, const int* in_sizes, int n_in,
                              void* d_out, int out_size, void* d_ws, size_t ws_size,
                              hipStream_t stream) {
  const float* x  = (const float*)d_in[0];
  const int*   ei = (const int*)d_in[1];
  const float* W1 = (const float*)d_in[2];
  const float* b1 = (const float*)d_in[3];
  const float* W2 = (const float*)d_in[4];
  const float* b2 = (const float*)d_in[5];
  const float* W3 = (const float*)d_in[6];
  const float* b3 = (const float*)d_in[7];
  int N = in_sizes[0] / D;
  int E = in_sizes[1] / 2;
  const int* srcp = ei;
  const int* dstp = ei + E;

  char* wp = (char*)d_ws;
  auto carve = [&](size_t bytes) {
    void* p = (void*)wp;
    wp += (bytes + 255) & ~(size_t)255;
    return p;
  };
  int*    cnt   = (int*)carve((size_t)N * 4);
  int*    off   = (int*)carve((size_t)(N + 1) * 4);
  int*    bsum  = (int*)carve(256 * 4);
  float*  dis   = (float*)carve((size_t)N * 4);
  uint2*  epack = (uint2*)carve((size_t)E * 8);
  ushort* xb    = (ushort*)carve((size_t)N * D * 2);
  ushort* t1    = (ushort*)carve((size_t)N * D * 2);
  ushort* t2    = (ushort*)carve((size_t)N * D * 2);
  ushort* wfall = (ushort*)carve((size_t)3 * 32768 * 2);
  ushort* wf1 = wfall, *wf2 = wfall + 32768, *wf3 = wfall + 65536;

  hipMemsetAsync(cnt, 0, (size_t)N * 4, stream);

  const int tb = 256;
  int total4 = N * D / 4;
  int xbB = (total4 + 255) / 256;
  int cntB = (E + 255) / 256;
  prep_kernel<<<xbB + cntB + 384, 256, 0, stream>>>(x, xb, total4, dstp, cnt, E,
                                                    W1, W2, W3, wfall, xbB, cntB);
  int nb = (N + SCHUNK - 1) / SCHUNK;
  scan1_kernel<<<nb, SB, 0, stream>>>(cnt, off, bsum, dis, N);
  scan3_kernel<<<(N + tb - 1) / tb, tb, 0, stream>>>(off, bsum, N, E);
  fill_kernel<<<(E + tb - 1) / tb, tb, 0, stream>>>(srcp, dstp, off, cnt, epack, dis, E);

  int fb = (N + 31) / 32;
  fused_kernel<0><<<fb, 128, 0, stream>>>(xb, epack, off, dis, wf1, b1, t1, N);
  fused_kernel<0><<<fb, 128, 0, stream>>>(t1, epack, off, dis, wf2, b2, t2, N);
  fused_kernel<1><<<fb, 128, 0, stream>>>(t2, epack, off, dis, wf3, b3, d_out, N);
}

// Round 14
// 222.654 us; speedup vs baseline: 1.3534x; 1.3534x over previous
//
#include <hip/hip_runtime.h>

#define D 128
#define SB 256
#define SI 8
#define SCHUNK (SB * SI)

typedef __attribute__((ext_vector_type(8))) short bf16x8;
typedef __attribute__((ext_vector_type(4))) float f32x4;
typedef unsigned int uint32;
typedef unsigned short ushort;

__device__ __forceinline__ ushort bf16rne(float f) {
  uint32 u = __float_as_uint(f);
  uint32 r = u + 0x7FFFu + ((u >> 16) & 1u);
  return (ushort)(r >> 16);
}
__device__ __forceinline__ float bf2f_lo(uint32 h) { return __uint_as_float(h << 16); }
__device__ __forceinline__ float bf2f_hi(uint32 h) { return __uint_as_float(h & 0xFFFF0000u); }
__device__ __forceinline__ uint32 packbf2(float x, float y) {
  return (uint32)bf16rne(x) | ((uint32)bf16rne(y) << 16);
}
__device__ __forceinline__ void acc8(float* a, float w, uint4 h) {
  a[0] += w * bf2f_lo(h.x); a[1] += w * bf2f_hi(h.x);
  a[2] += w * bf2f_lo(h.y); a[3] += w * bf2f_hi(h.y);
  a[4] += w * bf2f_lo(h.z); a[5] += w * bf2f_hi(h.z);
  a[6] += w * bf2f_lo(h.w); a[7] += w * bf2f_hi(h.w);
}

// ---------------- prep: xb convert + degree count + W-conv, one launch -----

__global__ void prep_kernel(const float* __restrict__ x, ushort* __restrict__ xb, int total4,
                            const int* __restrict__ dst, int* __restrict__ cnt, int E,
                            const float* __restrict__ W1, const float* __restrict__ W2,
                            const float* __restrict__ W3, ushort* __restrict__ Wf,
                            int xbB, int cntB) {
  int b = blockIdx.x;
  int tid = threadIdx.x;
  if (b < xbB) {
    int i = b * 256 + tid;
    if (i < total4) {
      float4 v = ((const float4*)x)[i];
      uint2 o;
      o.x = packbf2(v.x, v.y);
      o.y = packbf2(v.z, v.w);
      ((uint2*)xb)[i] = o;
    }
  } else if (b < xbB + cntB) {
    int e = (b - xbB) * 256 + tid;
    if (e < E) atomicAdd(&cnt[dst[e]], 1);
  } else {
    int idx = (b - xbB - cntB) * 256 + tid;  // 0..98303
    int which = idx >> 15;
    int id = idx & 32767;
    const float* W = (which == 0) ? W1 : ((which == 1) ? W2 : W3);
    int j = id & 7;
    int l = (id >> 3) & 63;
    int f = id >> 9;
    int p = f & 1, kc = (f >> 1) & 3, ct = f >> 3;
    int k = kc * 32 + (l >> 4) * 8 + j;
    int col = ct * 16 + (l & 15);
    float w = W[k * D + col];
    ushort hi = bf16rne(w);
    ushort outv = hi;
    if (p) {
      float hf = __uint_as_float((uint32)hi << 16);
      outv = bf16rne(w - hf);
    }
    Wf[idx] = outv;
  }
}

// ---------------- CSR build ----------------

__global__ void scan1_kernel(const int* __restrict__ cnt, int* __restrict__ off,
                             int* __restrict__ bsum, float* __restrict__ dis, int n) {
  __shared__ int tsum[SB];
  int tid = threadIdx.x;
  int base = blockIdx.x * SCHUNK;
  int v[SI];
  int s = 0;
#pragma unroll
  for (int i = 0; i < SI; i++) {
    int idx = base + tid * SI + i;
    v[i] = (idx < n) ? cnt[idx] : 0;
    s += v[i];
  }
  tsum[tid] = s;
  __syncthreads();
  for (int o = 1; o < SB; o <<= 1) {
    int t = (tid >= o) ? tsum[tid - o] : 0;
    __syncthreads();
    tsum[tid] += t;
    __syncthreads();
  }
  int run = tsum[tid] - s;
#pragma unroll
  for (int i = 0; i < SI; i++) {
    int idx = base + tid * SI + i;
    if (idx < n) {
      off[idx] = run;
      dis[idx] = rsqrtf((float)(v[i] + 1));
    }
    run += v[i];
  }
  if (tid == SB - 1) bsum[blockIdx.x] = tsum[tid];
}

// scan3: adds cross-chunk base (computed in-kernel from bsum; nb <= 64)
__global__ void scan3_kernel(int* __restrict__ off, const int* __restrict__ bsum,
                             int n, int total) {
  __shared__ int cbase;
  int b = blockIdx.x;
  int tid = threadIdx.x;
  int c = (b * 256) / SCHUNK;  // whole block lies in one chunk
  if (tid < 64) {
    int v = (tid < c) ? bsum[tid] : 0;
#pragma unroll
    for (int o = 32; o; o >>= 1) v += __shfl_down(v, o);
    if (tid == 0) cbase = v;
  }
  __syncthreads();
  int i = b * 256 + tid;
  if (i < n) off[i] += cbase;
  if (i == 0) off[n] = total;
}

// fill: uses cnt as countdown cursor (destroys it -> cnt ends all-zero)
__global__ void fill_kernel(const int* __restrict__ src, const int* __restrict__ dst,
                            const int* __restrict__ off, int* __restrict__ cnt,
                            uint2* __restrict__ epack, const float* __restrict__ dis, int E) {
  int e = blockIdx.x * blockDim.x + threadIdx.x;
  if (e >= E) return;
  int s = src[e], d = dst[e];
  int slot = atomicSub(&cnt[d], 1) - 1;
  int p = off[d] + slot;
  uint2 v;
  v.x = (uint32)s;
  v.y = __float_as_uint(dis[s] * dis[d]);
  epack[p] = v;
}

// ------- fused layer: out = [relu](Agg(t) @ W + bias) ----------------------
// gather-first. M=32 rows/block, 128 threads (2 waves).
// Register discipline for TRUE 8 waves/SIMD (no spill):
//  - gather phase ~56 regs (4-deep pipe, proven R12 logic)
//  - MFMA phase: af re-read per-kc from the live LDS A-tile (8 regs, not 16
//    held), acc split into two 4-col halves (16 AGPR), b-frags 16 transient.
//  - epilogue uses a SEPARATE LDS region so the A-tile stays valid across
//    both halves (no af[4] hoist needed).

template <int FINAL>
__global__ __launch_bounds__(128, 8) void fused_kernel(const ushort* __restrict__ t,
                                                       const uint2* __restrict__ epack,
                                                       const int* __restrict__ off,
                                                       const float* __restrict__ dis,
                                                       const ushort* __restrict__ Wf,
                                                       const float* __restrict__ bias,
                                                       void* __restrict__ outp, int N) {
  __shared__ char lds[FINAL ? 16384 : 12288];  // [0,8K) A-tile, [8K,..) epilogue
  int tid = threadIdx.x;
  int row0 = blockIdx.x * 32;
  int lane = tid & 63, wv = tid >> 6;  // wv 0..1
  int q = lane & 15, g = lane >> 4;
  int qb = q * 16;
  const char* tb = (const char*)t;

#pragma unroll 1
  for (int n4 = 0; n4 < 4; n4++) {
    int r = wv * 16 + n4 * 4 + g;  // 0..31
    int node = row0 + r;
    float a[8];
#pragma unroll
    for (int i = 0; i < 8; i++) a[i] = 0.f;

    if (node < N) {
      uint4 hs = *(const uint4*)(tb + (((uint32)node << 8) + qb));
      int j0 = off[node], j1 = off[node + 1];
      float dsv = dis[node];
      float sw = dsv * dsv;

      auto ldE = [&](int idx) -> uint2 {
        if (idx < j1) return epack[idx];
        uint2 z; z.x = (uint32)node; z.y = 0u; return z;  // self row, weight 0
      };
      int j = j0;
      uint2 e0 = ldE(j), e1 = ldE(j + 1), e2 = ldE(j + 2), e3 = ldE(j + 3);
      while (j < j1) {
        uint4 h0 = *(const uint4*)(tb + ((e0.x << 8) + qb));
        uint4 h1 = *(const uint4*)(tb + ((e1.x << 8) + qb));
        uint4 h2 = *(const uint4*)(tb + ((e2.x << 8) + qb));
        uint4 h3 = *(const uint4*)(tb + ((e3.x << 8) + qb));
        float w0 = __uint_as_float(e0.y), w1 = __uint_as_float(e1.y);
        float w2 = __uint_as_float(e2.y), w3 = __uint_as_float(e3.y);
        int jn = j + 4;
        e0 = ldE(jn); e1 = ldE(jn + 1); e2 = ldE(jn + 2); e3 = ldE(jn + 3);
        acc8(a, w0, h0);
        acc8(a, w1, h1);
        acc8(a, w2, h2);
        acc8(a, w3, h3);
        j = jn;
      }
      acc8(a, sw, hs);
    }
    uint4 pv;
    pv.x = packbf2(a[0], a[1]);
    pv.y = packbf2(a[2], a[3]);
    pv.z = packbf2(a[4], a[5]);
    pv.w = packbf2(a[6], a[7]);
    int boff = (r * 256 + qb) ^ ((r & 7) << 4);
    *(uint4*)(lds + boff) = pv;
  }
  __syncthreads();

  // ---- MFMA: z(32x128) @ W(128x128), two 4-column halves ----
  int lr = lane & 15, lg = lane >> 4;
  int m0 = wv * 16;
  int arow = m0 + lr;

#pragma unroll 1
  for (int hp = 0; hp < 2; hp++) {
    f32x4 acc4[4];
#pragma unroll
    for (int c4 = 0; c4 < 4; c4++) acc4[c4] = (f32x4){0.f, 0.f, 0.f, 0.f};

#pragma unroll 1
    for (int kc = 0; kc < 4; kc++) {
      bf16x8 af = *(bf16x8*)(lds + ((arow * 256 + kc * 64 + lg * 16) ^ ((arow & 7) << 4)));
#pragma unroll
      for (int c4 = 0; c4 < 4; c4++) {
        int ct = hp * 4 + c4;
        bf16x8 b0 = *(const bf16x8*)&Wf[(size_t)((((ct * 4 + kc) * 2 + 0) * 64 + lane) * 8)];
        bf16x8 b1 = *(const bf16x8*)&Wf[(size_t)((((ct * 4 + kc) * 2 + 1) * 64 + lane) * 8)];
        acc4[c4] = __builtin_amdgcn_mfma_f32_16x16x32_bf16(af, b0, acc4[c4], 0, 0, 0);
        acc4[c4] = __builtin_amdgcn_mfma_f32_16x16x32_bf16(af, b1, acc4[c4], 0, 0, 0);
      }
    }

    if (FINAL) {
      // fp32 epilogue for this 64-col half via [8K,16K) region
      char* ep = lds + 8192;
      float* out = (float*)outp;
#pragma unroll
      for (int c4 = 0; c4 < 4; c4++) {
        float bv = bias[(hp * 4 + c4) * 16 + lr];
#pragma unroll
        for (int r = 0; r < 4; r++) {
          int row = m0 + lg * 4 + r;
          int colb = c4 * 16 + lr;  // 0..63 within half
          float v = acc4[c4][r] + bv;
          int boff = (row * 256 + colb * 4) ^ ((row & 7) << 4);
          *(float*)(ep + boff) = v;
        }
      }
      __syncthreads();
#pragma unroll
      for (int i = 0; i < 4; i++) {
        int f = i * 2048 + tid * 16;  // 8KB: 32 rows x 256B half-rows
        int row = f >> 8;             // 0..31
        int boff = f ^ ((row & 7) << 4);
        if (row0 + row < N) {
          uint4 v = *(uint4*)(ep + boff);
          *(uint4*)((char*)out + (size_t)(row0 + row) * 512 + hp * 256 + (f & 255)) = v;
        }
      }
      __syncthreads();
    } else {
      // bf16 epilogue (bias+relu) for this 64-col half via [8K,12K) region
      char* ep = lds + 8192;
#pragma unroll
      for (int c4 = 0; c4 < 4; c4++) {
        int colb = c4 * 16 + lr;  // 0..63 within half
        float bv = bias[(hp * 4 + c4) * 16 + lr];
#pragma unroll
        for (int r = 0; r < 4; r++) {
          int row = m0 + lg * 4 + r;
          float v = fmaxf(acc4[c4][r] + bv, 0.f);
          int boff = (row * 128 + colb * 2) ^ ((row & 7) << 4);
          *(ushort*)(ep + boff) = bf16rne(v);
        }
      }
      __syncthreads();
      ushort* outb = (ushort*)outp;
#pragma unroll
      for (int i = 0; i < 2; i++) {
        int f2 = i * 2048 + tid * 16;  // 4KB: 32 rows x 128B half-rows
        int row = f2 >> 7;             // 0..31
        int cb = f2 & 127;
        int boff = (row * 128 + cb) ^ ((row & 7) << 4);
        if (row0 + row < N) {
          uint4 v = *(uint4*)(ep + boff);
          *(uint4*)((char*)outb + (size_t)(row0 + row) * 256 + hp * 128 + cb) = v;
        }
      }
      __syncthreads();
    }
  }
}

// ---------------- launch ----------------

extern "C" void kernel_launch(void* const* d_in, const int* in_sizes, int n_in,
                              void* d_out, int out_size, void* d_ws, size_t ws_size,
                              hipStream_t stream) {
  const float* x  = (const float*)d_in[0];
  const int*   ei = (const int*)d_in[1];
  const float* W1 = (const float*)d_in[2];
  const float* b1 = (const float*)d_in[3];
  const float* W2 = (const float*)d_in[4];
  const float* b2 = (const float*)d_in[5];
  const float* W3 = (const float*)d_in[6];
  const float* b3 = (const float*)d_in[7];
  int N = in_sizes[0] / D;
  int E = in_sizes[1] / 2;
  const int* srcp = ei;
  const int* dstp = ei + E;

  char* wp = (char*)d_ws;
  auto carve = [&](size_t bytes) {
    void* p = (void*)wp;
    wp += (bytes + 255) & ~(size_t)255;
    return p;
  };
  int*    cnt   = (int*)carve((size_t)N * 4);
  int*    off   = (int*)carve((size_t)(N + 1) * 4);
  int*    bsum  = (int*)carve(256 * 4);
  float*  dis   = (float*)carve((size_t)N * 4);
  uint2*  epack = (uint2*)carve((size_t)E * 8);
  ushort* xb    = (ushort*)carve((size_t)N * D * 2);
  ushort* t1    = (ushort*)carve((size_t)N * D * 2);
  ushort* t2    = (ushort*)carve((size_t)N * D * 2);
  ushort* wfall = (ushort*)carve((size_t)3 * 32768 * 2);
  ushort* wf1 = wfall, *wf2 = wfall + 32768, *wf3 = wfall + 65536;

  hipMemsetAsync(cnt, 0, (size_t)N * 4, stream);

  const int tb = 256;
  int total4 = N * D / 4;
  int xbB = (total4 + 255) / 256;
  int cntB = (E + 255) / 256;
  prep_kernel<<<xbB + cntB + 384, 256, 0, stream>>>(x, xb, total4, dstp, cnt, E,
                                                    W1, W2, W3, wfall, xbB, cntB);
  int nb = (N + SCHUNK - 1) / SCHUNK;
  scan1_kernel<<<nb, SB, 0, stream>>>(cnt, off, bsum, dis, N);
  scan3_kernel<<<(N + tb - 1) / tb, tb, 0, stream>>>(off, bsum, N, E);
  fill_kernel<<<(E + tb - 1) / tb, tb, 0, stream>>>(srcp, dstp, off, cnt, epack, dis, E);

  int fb = (N + 31) / 32;
  fused_kernel<0><<<fb, 128, 0, stream>>>(xb, epack, off, dis, wf1, b1, t1, N);
  fused_kernel<0><<<fb, 128, 0, stream>>>(t1, epack, off, dis, wf2, b2, t2, N);
  fused_kernel<1><<<fb, 128, 0, stream>>>(t2, epack, off, dis, wf3, b3, d_out, N);
}